// Round 7
// baseline (133.563 us; speedup 1.0000x reference)
//
#include <hip/hip_runtime.h>

typedef __attribute__((ext_vector_type(8))) short short8;
typedef __attribute__((ext_vector_type(4))) short short4v;
typedef __attribute__((ext_vector_type(4))) float f32x4;

#define T_ 2048
#define H_ 16
#define KVH_ 4
#define QSCALE 0.18033688011112042f   // 0.125 * log2(e): softmax in base-2 domain
#define DEFER 8.0f                    // T13 defer-max threshold (log2 domain)

__device__ inline unsigned short f2bf(float f) {
    unsigned u = __builtin_bit_cast(unsigned, f);
    u += 0x7fff + ((u >> 16) & 1);
    return (unsigned short)(u >> 16);
}
__device__ inline float bf2f(unsigned short v) {
    unsigned u = ((unsigned)v) << 16;
    return __builtin_bit_cast(float, u);
}

__device__ inline void gl_lds16(const unsigned short* g, unsigned short* lds) {
    __builtin_amdgcn_global_load_lds(
        (const __attribute__((address_space(1))) unsigned int*)g,
        (__attribute__((address_space(3))) unsigned int*)lds, 16, 0, 0);
}

// ---------------------------------------------------------------------------
// f32 -> bf16 straight cast (8 elems/thread)
// ---------------------------------------------------------------------------
__global__ void cast_bf16(const float* __restrict__ in,
                          unsigned short* __restrict__ out, int n8) {
    int i = blockIdx.x * blockDim.x + threadIdx.x;
    if (i >= n8) return;
    float4 v0 = ((const float4*)in)[i * 2];
    float4 v1 = ((const float4*)in)[i * 2 + 1];
    short8 o;
    o[0] = f2bf(v0.x); o[1] = f2bf(v0.y); o[2] = f2bf(v0.z); o[3] = f2bf(v0.w);
    o[4] = f2bf(v1.x); o[5] = f2bf(v1.y); o[6] = f2bf(v1.z); o[7] = f2bf(v1.w);
    ((short8*)out)[i] = o;
}

// ---------------------------------------------------------------------------
// W [K][N] f32  ->  out [rowoff + N][K] bf16   (transpose + cast), 64x64 tiles
// ---------------------------------------------------------------------------
__global__ __launch_bounds__(256) void transpose_cast(
        const float* __restrict__ W, unsigned short* __restrict__ out,
        int K, int N, int rowoff) {
    __shared__ unsigned short ts[64][66];
    const int bx = blockIdx.x, by = blockIdx.y, tid = threadIdx.x;
    #pragma unroll
    for (int s = 0; s < 16; ++s) {
        int idx = tid + s * 256;
        int kl = idx >> 6, nl = idx & 63;
        ts[kl][nl] = f2bf(W[(size_t)(by * 64 + kl) * N + bx * 64 + nl]);
    }
    __syncthreads();
    #pragma unroll
    for (int s = 0; s < 16; ++s) {
        int idx = tid + s * 256;
        int nl = idx >> 6, kl = idx & 63;
        out[(size_t)(rowoff + bx * 64 + nl) * K + by * 64 + kl] = ts[kl][nl];
    }
}

// ---------------------------------------------------------------------------
// bf16 MFMA GEMM, 128x64 tile, BK=32, global_load_lds staging, 4 waves x 32row.
// MODE 0: C = f32 [M][1024]  (O projection)
// MODE 1: merged QKV (N=1536): col-group <16: Q RoPE*QSCALE -> Cq [B][16][T][64]
//         16..19: K RoPE -> Ck [B][4][T][64];  20..23: V -> Cvt [B][4][64][T]
// ---------------------------------------------------------------------------
template <int MODE>
__global__ __launch_bounds__(256) void gemm_mfma(
        const unsigned short* __restrict__ A,
        const unsigned short* __restrict__ Bt,
        void* __restrict__ Cq, unsigned short* __restrict__ Ck,
        unsigned short* __restrict__ Cvt,
        const float* __restrict__ rc, const float* __restrict__ rs,
        int M, int N, int K) {
    __shared__ __align__(16) unsigned short As[128 * 32];
    __shared__ __align__(16) unsigned short Bs[64 * 32];
    const int tid = threadIdx.x;
    const int w = tid >> 6, l = tid & 63, lk = l & 15, lg = l >> 4;
    const int bx = blockIdx.x, by = blockIdx.y;

    const unsigned short* Arow = A + (size_t)by * 128 * K;
    const unsigned short* Brow = Bt + (size_t)bx * 64 * K;

    f32x4 acc[2][4];
    #pragma unroll
    for (int m = 0; m < 2; ++m)
        #pragma unroll
        for (int n = 0; n < 4; ++n) acc[m][n] = (f32x4){0, 0, 0, 0};

    for (int k0 = 0; k0 < K; k0 += 32) {
        #pragma unroll
        for (int p = 0; p < 2; ++p) {
            int cb = p * 256 + w * 64;
            int c = cb + l;
            int row = c >> 2, ko = (c & 3) * 8;
            gl_lds16(Arow + (size_t)row * K + k0 + ko, As + cb * 8);
        }
        {
            int c = w * 64 + l;
            int row = c >> 2, ko = (c & 3) * 8;
            gl_lds16(Brow + (size_t)row * K + k0 + ko, Bs + c * 8);
        }
        __syncthreads();
        short8 aF[2], bF[4];
        #pragma unroll
        for (int m = 0; m < 2; ++m)
            aF[m] = *(const short8*)&As[(w * 32 + m * 16 + lk) * 32 + lg * 8];
        #pragma unroll
        for (int n = 0; n < 4; ++n)
            bF[n] = *(const short8*)&Bs[(n * 16 + lk) * 32 + lg * 8];
        #pragma unroll
        for (int m = 0; m < 2; ++m)
            #pragma unroll
            for (int n = 0; n < 4; ++n)
                acc[m][n] = __builtin_amdgcn_mfma_f32_16x16x32_bf16(
                    aF[m], bF[n], acc[m][n], 0, 0, 0);
        __syncthreads();
    }

    const int rowbase = by * 128 + w * 32;
    if constexpr (MODE == 0) {
        float* C = (float*)Cq;
        #pragma unroll
        for (int m = 0; m < 2; ++m)
            #pragma unroll
            for (int r = 0; r < 4; ++r) {
                size_t ro = (size_t)(rowbase + m * 16 + lg * 4 + r) * N + bx * 64 + lk;
                #pragma unroll
                for (int n = 0; n < 4; ++n) C[ro + n * 16] = acc[m][n][r];
            }
    }
    if constexpr (MODE == 1) {
        const int colgrp = bx;              // 64-col group over N=1536
        if (colgrp < 16) {                  // ---- Q: RoPE * QSCALE
            unsigned short* C = (unsigned short*)Cq;
            const int h = colgrp;
            #pragma unroll
            for (int m = 0; m < 2; ++m)
                #pragma unroll
                for (int r = 0; r < 4; ++r) {
                    int trow = rowbase + m * 16 + lg * 4 + r;
                    int b = trow >> 11, t = trow & (T_ - 1);
                    size_t ob = (((size_t)(b * 16 + h)) * T_ + t) * 64;
                    #pragma unroll
                    for (int n = 0; n < 2; ++n) {
                        int d = n * 16 + lk;
                        float cc = rc[t * 32 + d], ss = rs[t * 32 + d];
                        float x1 = acc[m][n][r], x2 = acc[m][n + 2][r];
                        C[ob + d]      = f2bf((x1 * cc - x2 * ss) * QSCALE);
                        C[ob + d + 32] = f2bf((x2 * cc + x1 * ss) * QSCALE);
                    }
                }
        } else if (colgrp < 20) {           // ---- K: RoPE
            const int kvh = colgrp - 16;
            #pragma unroll
            for (int m = 0; m < 2; ++m)
                #pragma unroll
                for (int r = 0; r < 4; ++r) {
                    int trow = rowbase + m * 16 + lg * 4 + r;
                    int b = trow >> 11, t = trow & (T_ - 1);
                    size_t ob = (((size_t)(b * 4 + kvh)) * T_ + t) * 64;
                    #pragma unroll
                    for (int n = 0; n < 2; ++n) {
                        int d = n * 16 + lk;
                        float cc = rc[t * 32 + d], ss = rs[t * 32 + d];
                        float x1 = acc[m][n][r], x2 = acc[m][n + 2][r];
                        Ck[ob + d]      = f2bf(x1 * cc - x2 * ss);
                        Ck[ob + d + 32] = f2bf(x2 * cc + x1 * ss);
                    }
                }
        } else {                            // ---- V -> [B][4][64][T]
            const int kvh = colgrp - 20;
            #pragma unroll
            for (int m = 0; m < 2; ++m) {
                int trow0 = rowbase + m * 16 + lg * 4;
                int b = trow0 >> 11, t0 = trow0 & (T_ - 1);
                #pragma unroll
                for (int n = 0; n < 4; ++n) {
                    int d = n * 16 + lk;
                    short4v pk;
                    #pragma unroll
                    for (int r = 0; r < 4; ++r) pk[r] = f2bf(acc[m][n][r]);
                    *(short4v*)(Cvt + (((size_t)(b * 4 + kvh)) * 64 + d) * T_ + t0) = pk;
                }
            }
        }
    }
}

// ---------------------------------------------------------------------------
// Flash attention v5: split-K (flash-decoding). Every block <= 16 K-tiles.
//   ids    0..511 : long qt (16..31), chunk0 = tiles [0,16)   -> partial 0
//   ids  512..1023: short qt (15..0), all tiles               -> direct O
//   ids 1024..1535: long qt (31..16), chunk1 = tiles [16,qt]  -> partial 1
// Partials: unnormalized acc (bf16) + m,l (f32). Combine kernel merges.
// ---------------------------------------------------------------------------
#define SW(row, col) ((col) ^ (((row) & 7) << 3))

__global__ __launch_bounds__(256) void attn_mfma(
        const unsigned short* __restrict__ Q,   // [B][16][T][64] (pre-scaled, log2 domain)
        const unsigned short* __restrict__ K,   // [B][4][T][64]
        const unsigned short* __restrict__ Vt,  // [B][4][64][T]
        unsigned short* __restrict__ O,         // [B*T][16][64] bf16
        float* __restrict__ PM, float* __restrict__ PLp,
        unsigned short* __restrict__ PACC) {
    __shared__ __align__(16) unsigned short Ks[2][64][64];
    __shared__ __align__(16) unsigned short Vs[2][64][64];
    __shared__ __align__(16) unsigned short Pl[4][16][64];

    const int bid = blockIdx.x;
    int bh, qt, kt0, nkt, ck;
    bool direct;
    if (bid < 512) {
        bh = bid & 31; qt = 16 + ((bid >> 5) & 15);
        kt0 = 0; nkt = 16; ck = 0; direct = false;
    } else if (bid < 1024) {
        int j = bid - 512;
        bh = j & 31; qt = 15 - ((j >> 5) & 15);
        kt0 = 0; nkt = qt + 1; ck = 0; direct = true;
    } else {
        int j = bid - 1024;
        bh = j & 31; qt = 31 - ((j >> 5) & 15);
        kt0 = 16; nkt = qt - 15; ck = 1; direct = false;
    }
    const int h = bh & 15;
    const int b = bh >> 4;
    const int kv = h >> 2;
    const int tid = threadIdx.x;
    const int w = tid >> 6, l = tid & 63;
    const int lk = l & 15, lg = l >> 4;

    const unsigned short* Kb = K + ((size_t)(b * 4 + kv)) * T_ * 64;
    const unsigned short* Vb = Vt + ((size_t)(b * 4 + kv)) * 64 * T_;

    short8 af0, af1;
    {
        const unsigned short* q0 =
            Q + (((size_t)(b * 16 + h)) * T_ + qt * 64 + w * 16 + lk) * 64 + lg * 8;
        af0 = *(const short8*)(q0);
        af1 = *(const short8*)(q0 + 32);
    }

    f32x4 acc[4];
    f32x4 lacc = {0, 0, 0, 0};
    float mrow[4];
    #pragma unroll
    for (int db = 0; db < 4; ++db) acc[db] = (f32x4){0, 0, 0, 0};
    #pragma unroll
    for (int r = 0; r < 4; ++r) mrow[r] = -1e38f;

    short8 ones;
    #pragma unroll
    for (int i = 0; i < 8; ++i) ones[i] = (short)0x3F80;   // bf16 1.0

    const int srow = tid >> 2;            // 0..63
    const int soff = (tid & 3) * 16;      // 0,16,32,48

    short8 kr0, kr1, vr0, vr1;
    auto load_kv = [&](int kt) {
        const unsigned short* kg = Kb + ((size_t)(kt * 64 + srow)) * 64 + soff;
        kr0 = *(const short8*)(kg);
        kr1 = *(const short8*)(kg + 8);
        const unsigned short* vg = Vb + (size_t)srow * T_ + kt * 64 + soff;
        vr0 = *(const short8*)(vg);
        vr1 = *(const short8*)(vg + 8);
    };
    auto write_kv = [&](int buf) {
        *(short8*)(&Ks[buf][srow][SW(srow, soff)])     = kr0;
        *(short8*)(&Ks[buf][srow][SW(srow, soff + 8)]) = kr1;
        *(short8*)(&Vs[buf][srow][SW(srow, soff)])     = vr0;
        *(short8*)(&Vs[buf][srow][SW(srow, soff + 8)]) = vr1;
    };

    load_kv(kt0);
    write_kv(0);
    for (int i = 0; i < nkt; ++i) {
        const int kt = kt0 + i;
        const int cur = i & 1;
        __syncthreads();                        // staging of buf[cur] visible
        const bool pf = i < nkt - 1;
        if (pf) load_kv(kt + 1);                // issue early (T14)

        // ---- S = Q K^T
        float s4[4][4];
        __builtin_amdgcn_s_setprio(1);
        #pragma unroll
        for (int nt = 0; nt < 4; ++nt) {
            const int row = nt * 16 + lk;
            short8 b0 = *(const short8*)(&Ks[cur][row][SW(row, lg * 8)]);
            short8 b1 = *(const short8*)(&Ks[cur][row][SW(row, 32 + lg * 8)]);
            f32x4 c = {0, 0, 0, 0};
            c = __builtin_amdgcn_mfma_f32_16x16x32_bf16(af0, b0, c, 0, 0, 0);
            c = __builtin_amdgcn_mfma_f32_16x16x32_bf16(af1, b1, c, 0, 0, 0);
            #pragma unroll
            for (int r = 0; r < 4; ++r) s4[nt][r] = c[r];
        }
        __builtin_amdgcn_s_setprio(0);

        if (kt == qt) {                         // diagonal mask (last chunk only)
            int qloc = w * 16 + lg * 4;
            #pragma unroll
            for (int nt = 0; nt < 4; ++nt) {
                int kloc = nt * 16 + lk;
                #pragma unroll
                for (int r = 0; r < 4; ++r)
                    if (kloc > qloc + r) s4[nt][r] = -1e30f;
            }
        }

        // ---- online softmax with defer-max (T13)
        float rm[4];
        #pragma unroll
        for (int r = 0; r < 4; ++r) {
            float v = fmaxf(fmaxf(s4[0][r], s4[1][r]), fmaxf(s4[2][r], s4[3][r]));
            v = fmaxf(v, __shfl_xor(v, 1));
            v = fmaxf(v, __shfl_xor(v, 2));
            v = fmaxf(v, __shfl_xor(v, 4));
            v = fmaxf(v, __shfl_xor(v, 8));
            rm[r] = v;
        }
        bool need = (rm[0] > mrow[0] + DEFER) || (rm[1] > mrow[1] + DEFER) ||
                    (rm[2] > mrow[2] + DEFER) || (rm[3] > mrow[3] + DEFER);
        if (__any(need)) {
            #pragma unroll
            for (int r = 0; r < 4; ++r) {
                float nm = fmaxf(mrow[r], rm[r]);
                float corr = exp2f(mrow[r] - nm);
                mrow[r] = nm;
                #pragma unroll
                for (int db = 0; db < 4; ++db) acc[db][r] *= corr;
                lacc[r] *= corr;
            }
        }
        #pragma unroll
        for (int r = 0; r < 4; ++r)
            #pragma unroll
            for (int nt = 0; nt < 4; ++nt) s4[nt][r] = exp2f(s4[nt][r] - mrow[r]);

        #pragma unroll
        for (int nt = 0; nt < 4; ++nt)
            #pragma unroll
            for (int r = 0; r < 4; ++r) {
                int row = lg * 4 + r;
                Pl[w][row][SW(row, nt * 16 + lk)] = f2bf(s4[nt][r]);
            }

        if (pf) write_kv(cur ^ 1);              // write late, covered by compute

        // ---- O += P V ; lsum += P 1
        __builtin_amdgcn_s_setprio(1);
        #pragma unroll
        for (int kk = 0; kk < 2; ++kk) {
            short8 pa = *(const short8*)(&Pl[w][lk][SW(lk, kk * 32 + lg * 8)]);
            lacc = __builtin_amdgcn_mfma_f32_16x16x32_bf16(pa, ones, lacc, 0, 0, 0);
            #pragma unroll
            for (int db = 0; db < 4; ++db) {
                const int row = db * 16 + lk;
                short8 vb = *(const short8*)(&Vs[cur][row][SW(row, kk * 32 + lg * 8)]);
                acc[db] = __builtin_amdgcn_mfma_f32_16x16x32_bf16(pa, vb, acc[db], 0, 0, 0);
            }
        }
        __builtin_amdgcn_s_setprio(0);
    }

    if (direct) {
        #pragma unroll
        for (int r = 0; r < 4; ++r) {
            float inv = 1.f / lacc[r];
            int t = qt * 64 + w * 16 + lg * 4 + r;
            #pragma unroll
            for (int db = 0; db < 4; ++db)
                O[(((size_t)(b * T_ + t)) * 16 + h) * 64 + db * 16 + lk] =
                    f2bf(acc[db][r] * inv);
        }
    } else {
        const int p = ((bh << 4) + (qt - 16)) * 2 + ck;
        #pragma unroll
        for (int r = 0; r < 4; ++r) {
            int row = w * 16 + lg * 4 + r;
            if (lk == 0) {
                PM[p * 64 + row]  = mrow[r];
                PLp[p * 64 + row] = lacc[r];
            }
            #pragma unroll
            for (int db = 0; db < 4; ++db)
                PACC[((size_t)p * 64 + row) * 64 + db * 16 + lk] = f2bf(acc[db][r]);
        }
    }
}

// ---------------------------------------------------------------------------
// Combine two split-K partials per (b,h,long-qt).  512 blocks x 256 threads.
// ---------------------------------------------------------------------------
__global__ __launch_bounds__(256) void combine_attn(
        const float* __restrict__ PM, const float* __restrict__ PLp,
        const unsigned short* __restrict__ PACC,
        unsigned short* __restrict__ O) {
    const int cid = blockIdx.x;
    const int bh = cid & 31, qt = 16 + (cid >> 5);
    const int h = bh & 15, b = bh >> 4;
    const int tid = threadIdx.x;
    const int rr = tid >> 2, cg = (tid & 3) * 16;
    const int p0 = ((bh << 4) + (qt - 16)) * 2, p1 = p0 + 1;

    float mA = PM[p0 * 64 + rr], mB = PM[p1 * 64 + rr];
    float lA = PLp[p0 * 64 + rr], lB = PLp[p1 * 64 + rr];
    float M = fmaxf(mA, mB);
    float wA = exp2f(mA - M), wB = exp2f(mB - M);
    float inv = 1.f / (lA * wA + lB * wB);
    wA *= inv; wB *= inv;

    const unsigned short* a = &PACC[((size_t)p0 * 64 + rr) * 64 + cg];
    const unsigned short* c = &PACC[((size_t)p1 * 64 + rr) * 64 + cg];
    short8 va0 = *(const short8*)a, va1 = *(const short8*)(a + 8);
    short8 vb0 = *(const short8*)c, vb1 = *(const short8*)(c + 8);
    short8 o0, o1;
    #pragma unroll
    for (int i = 0; i < 8; ++i) {
        o0[i] = f2bf(bf2f((unsigned short)va0[i]) * wA + bf2f((unsigned short)vb0[i]) * wB);
        o1[i] = f2bf(bf2f((unsigned short)va1[i]) * wA + bf2f((unsigned short)vb1[i]) * wB);
    }
    int t = qt * 64 + rr;
    unsigned short* op = &O[(((size_t)(b * T_ + t)) * 16 + h) * 64 + cg];
    *(short8*)op = o0;
    *(short8*)(op + 8) = o1;
}

// ---------------------------------------------------------------------------
extern "C" void kernel_launch(void* const* d_in, const int* in_sizes, int n_in,
                              void* d_out, int out_size, void* d_ws, size_t ws_size,
                              hipStream_t stream) {
    const float* x  = (const float*)d_in[0];
    const float* rc = (const float*)d_in[1];
    const float* rs = (const float*)d_in[2];
    const float* Wq = (const float*)d_in[4];
    const float* Wk = (const float*)d_in[5];
    const float* Wv = (const float*)d_in[6];
    const float* Wo = (const float*)d_in[7];
    float* out = (float*)d_out;

    unsigned short* ws = (unsigned short*)d_ws;
    unsigned short* xb  = ws;                        // 4M shorts
    unsigned short* Wt  = ws + 4194304;              // 1536x1024 = 1.5M
    unsigned short* Wot = ws + 5767168;              // 1M
    unsigned short* Qbf = ws + 6815744;              // 4M
    unsigned short* Kbf = ws + 11010048;             // 1M
    unsigned short* Vtb = ws + 12058624;             // 1M
    unsigned short* Ob  = ws + 13107200;             // 4M

    // split-K partial buffers: reuse xb/Wt region (dead after QKV gemm)
    float* PM          = (float*)d_ws;               // [1024][64] f32
    float* PLp         = PM + 1024 * 64;             // [1024][64] f32
    unsigned short* PACC = (unsigned short*)(PLp + 1024 * 64);  // [1024][64][64] bf16

    dim3 blk(256);
    cast_bf16<<<2048, blk, 0, stream>>>(x, xb, 524288);
    transpose_cast<<<dim3(16, 16), blk, 0, stream>>>(Wq, Wt, 1024, 1024, 0);
    transpose_cast<<<dim3(4, 16),  blk, 0, stream>>>(Wk, Wt, 1024, 256, 1024);
    transpose_cast<<<dim3(4, 16),  blk, 0, stream>>>(Wv, Wt, 1024, 256, 1280);
    transpose_cast<<<dim3(16, 16), blk, 0, stream>>>(Wo, Wot, 1024, 1024, 0);

    gemm_mfma<1><<<dim3(24, 32), blk, 0, stream>>>(
        xb, Wt, (void*)Qbf, Kbf, Vtb, rc, rs, 4096, 1536, 1024);

    attn_mfma<<<dim3(1536), blk, 0, stream>>>(Qbf, Kbf, Vtb, Ob, PM, PLp, PACC);
    combine_attn<<<dim3(512), blk, 0, stream>>>(PM, PLp, PACC, Ob);

    gemm_mfma<0><<<dim3(16, 32), blk, 0, stream>>>(
        Ob, Wot, (void*)out, nullptr, nullptr, nullptr, nullptr, 4096, 1024, 1024);
}

// Round 8
// 125.994 us; speedup vs baseline: 1.0601x; 1.0601x over previous
//
#include <hip/hip_runtime.h>

typedef __attribute__((ext_vector_type(8))) short short8;
typedef __attribute__((ext_vector_type(4))) short short4v;
typedef __attribute__((ext_vector_type(4))) float f32x4;

#define T_ 2048
#define H_ 16
#define KVH_ 4
#define QSCALE 0.18033688011112042f   // 0.125 * log2(e): softmax in base-2 domain
#define DEFER 8.0f                    // T13 defer-max threshold (log2 domain)

__device__ inline unsigned short f2bf(float f) {
    unsigned u = __builtin_bit_cast(unsigned, f);
    u += 0x7fff + ((u >> 16) & 1);
    return (unsigned short)(u >> 16);
}
__device__ inline float bf2f(unsigned short v) {
    unsigned u = ((unsigned)v) << 16;
    return __builtin_bit_cast(float, u);
}

__device__ inline void gl_lds16(const unsigned short* g, unsigned short* lds) {
    __builtin_amdgcn_global_load_lds(
        (const __attribute__((address_space(1))) unsigned int*)g,
        (__attribute__((address_space(3))) unsigned int*)lds, 16, 0, 0);
}

// ---------------------------------------------------------------------------
// f32 -> bf16 straight cast (8 elems/thread)
// ---------------------------------------------------------------------------
__global__ void cast_bf16(const float* __restrict__ in,
                          unsigned short* __restrict__ out, int n8) {
    int i = blockIdx.x * blockDim.x + threadIdx.x;
    if (i >= n8) return;
    float4 v0 = ((const float4*)in)[i * 2];
    float4 v1 = ((const float4*)in)[i * 2 + 1];
    short8 o;
    o[0] = f2bf(v0.x); o[1] = f2bf(v0.y); o[2] = f2bf(v0.z); o[3] = f2bf(v0.w);
    o[4] = f2bf(v1.x); o[5] = f2bf(v1.y); o[6] = f2bf(v1.z); o[7] = f2bf(v1.w);
    ((short8*)out)[i] = o;
}

// ---------------------------------------------------------------------------
// W [K][N] f32  ->  out [rowoff + N][K] bf16   (transpose + cast), 64x64 tiles
// ---------------------------------------------------------------------------
__global__ __launch_bounds__(256) void transpose_cast(
        const float* __restrict__ W, unsigned short* __restrict__ out,
        int K, int N, int rowoff) {
    __shared__ unsigned short ts[64][66];
    const int bx = blockIdx.x, by = blockIdx.y, tid = threadIdx.x;
    #pragma unroll
    for (int s = 0; s < 16; ++s) {
        int idx = tid + s * 256;
        int kl = idx >> 6, nl = idx & 63;
        ts[kl][nl] = f2bf(W[(size_t)(by * 64 + kl) * N + bx * 64 + nl]);
    }
    __syncthreads();
    #pragma unroll
    for (int s = 0; s < 16; ++s) {
        int idx = tid + s * 256;
        int nl = idx >> 6, kl = idx & 63;
        out[(size_t)(rowoff + bx * 64 + nl) * K + by * 64 + kl] = ts[kl][nl];
    }
}

// ---------------------------------------------------------------------------
// bf16 MFMA GEMM, 128x64 tile, BK=32, global_load_lds staging, 4 waves x 32row.
// MODE 0: C = f32 [M][1024]  (O projection)
// MODE 1: merged QKV (N=1536): col-group <16: Q RoPE*QSCALE -> Cq [B][16][T][64]
//         16..19: K RoPE -> Ck [B][4][T][64];  20..23: V -> Cvt [B][4][64][T]
// ---------------------------------------------------------------------------
template <int MODE>
__global__ __launch_bounds__(256) void gemm_mfma(
        const unsigned short* __restrict__ A,
        const unsigned short* __restrict__ Bt,
        void* __restrict__ Cq, unsigned short* __restrict__ Ck,
        unsigned short* __restrict__ Cvt,
        const float* __restrict__ rc, const float* __restrict__ rs,
        int M, int N, int K) {
    __shared__ __align__(16) unsigned short As[128 * 32];
    __shared__ __align__(16) unsigned short Bs[64 * 32];
    const int tid = threadIdx.x;
    const int w = tid >> 6, l = tid & 63, lk = l & 15, lg = l >> 4;
    const int bx = blockIdx.x, by = blockIdx.y;

    const unsigned short* Arow = A + (size_t)by * 128 * K;
    const unsigned short* Brow = Bt + (size_t)bx * 64 * K;

    f32x4 acc[2][4];
    #pragma unroll
    for (int m = 0; m < 2; ++m)
        #pragma unroll
        for (int n = 0; n < 4; ++n) acc[m][n] = (f32x4){0, 0, 0, 0};

    for (int k0 = 0; k0 < K; k0 += 32) {
        #pragma unroll
        for (int p = 0; p < 2; ++p) {
            int cb = p * 256 + w * 64;
            int c = cb + l;
            int row = c >> 2, ko = (c & 3) * 8;
            gl_lds16(Arow + (size_t)row * K + k0 + ko, As + cb * 8);
        }
        {
            int c = w * 64 + l;
            int row = c >> 2, ko = (c & 3) * 8;
            gl_lds16(Brow + (size_t)row * K + k0 + ko, Bs + c * 8);
        }
        __syncthreads();
        short8 aF[2], bF[4];
        #pragma unroll
        for (int m = 0; m < 2; ++m)
            aF[m] = *(const short8*)&As[(w * 32 + m * 16 + lk) * 32 + lg * 8];
        #pragma unroll
        for (int n = 0; n < 4; ++n)
            bF[n] = *(const short8*)&Bs[(n * 16 + lk) * 32 + lg * 8];
        #pragma unroll
        for (int m = 0; m < 2; ++m)
            #pragma unroll
            for (int n = 0; n < 4; ++n)
                acc[m][n] = __builtin_amdgcn_mfma_f32_16x16x32_bf16(
                    aF[m], bF[n], acc[m][n], 0, 0, 0);
        __syncthreads();
    }

    const int rowbase = by * 128 + w * 32;
    if constexpr (MODE == 0) {
        float* C = (float*)Cq;
        #pragma unroll
        for (int m = 0; m < 2; ++m)
            #pragma unroll
            for (int r = 0; r < 4; ++r) {
                size_t ro = (size_t)(rowbase + m * 16 + lg * 4 + r) * N + bx * 64 + lk;
                #pragma unroll
                for (int n = 0; n < 4; ++n) C[ro + n * 16] = acc[m][n][r];
            }
    }
    if constexpr (MODE == 1) {
        const int colgrp = bx;              // 64-col group over N=1536
        if (colgrp < 16) {                  // ---- Q: RoPE * QSCALE
            unsigned short* C = (unsigned short*)Cq;
            const int h = colgrp;
            #pragma unroll
            for (int m = 0; m < 2; ++m)
                #pragma unroll
                for (int r = 0; r < 4; ++r) {
                    int trow = rowbase + m * 16 + lg * 4 + r;
                    int b = trow >> 11, t = trow & (T_ - 1);
                    size_t ob = (((size_t)(b * 16 + h)) * T_ + t) * 64;
                    #pragma unroll
                    for (int n = 0; n < 2; ++n) {
                        int d = n * 16 + lk;
                        float cc = rc[t * 32 + d], ss = rs[t * 32 + d];
                        float x1 = acc[m][n][r], x2 = acc[m][n + 2][r];
                        C[ob + d]      = f2bf((x1 * cc - x2 * ss) * QSCALE);
                        C[ob + d + 32] = f2bf((x2 * cc + x1 * ss) * QSCALE);
                    }
                }
        } else if (colgrp < 20) {           // ---- K: RoPE
            const int kvh = colgrp - 16;
            #pragma unroll
            for (int m = 0; m < 2; ++m)
                #pragma unroll
                for (int r = 0; r < 4; ++r) {
                    int trow = rowbase + m * 16 + lg * 4 + r;
                    int b = trow >> 11, t = trow & (T_ - 1);
                    size_t ob = (((size_t)(b * 4 + kvh)) * T_ + t) * 64;
                    #pragma unroll
                    for (int n = 0; n < 2; ++n) {
                        int d = n * 16 + lk;
                        float cc = rc[t * 32 + d], ss = rs[t * 32 + d];
                        float x1 = acc[m][n][r], x2 = acc[m][n + 2][r];
                        Ck[ob + d]      = f2bf(x1 * cc - x2 * ss);
                        Ck[ob + d + 32] = f2bf(x2 * cc + x1 * ss);
                    }
                }
        } else {                            // ---- V -> [B][4][64][T]
            const int kvh = colgrp - 20;
            #pragma unroll
            for (int m = 0; m < 2; ++m) {
                int trow0 = rowbase + m * 16 + lg * 4;
                int b = trow0 >> 11, t0 = trow0 & (T_ - 1);
                #pragma unroll
                for (int n = 0; n < 4; ++n) {
                    int d = n * 16 + lk;
                    short4v pk;
                    #pragma unroll
                    for (int r = 0; r < 4; ++r) pk[r] = f2bf(acc[m][n][r]);
                    *(short4v*)(Cvt + (((size_t)(b * 4 + kvh)) * 64 + d) * T_ + t0) = pk;
                }
            }
        }
    }
}

// ---------------------------------------------------------------------------
// Flash attention v6: 128 q-rows/block (4 waves x 32 rows) -> K/V fragment
// redundancy halved. global_load_lds staging with pre-swizzled global source
// (linear LDS dest). Lane-local defer check (shuffle-free common path).
// Split-K: long q-tiles (qt 8..15) in two chunks of <=16 key-tiles.
//   bid   0..255 : chunk0 (kt 0..15) of qt 8..15   -> partial ck=0
//   bid 256..511 : direct qt 7..0 (all kt)         -> O
//   bid 512..767 : chunk1 (kt 16..2qt+1) qt 15..8  -> partial ck=1
// ---------------------------------------------------------------------------
#define SWC(row, col) ((col) ^ (((row) & 7) << 3))

__global__ __launch_bounds__(256) void attn_mfma(
        const unsigned short* __restrict__ Q,   // [B][16][T][64] (pre-scaled, log2 domain)
        const unsigned short* __restrict__ K,   // [B][4][T][64]
        const unsigned short* __restrict__ Vt,  // [B][4][64][T]
        unsigned short* __restrict__ O,         // [B*T][16][64] bf16
        float* __restrict__ PM, float* __restrict__ PLp,
        unsigned short* __restrict__ PACC) {
    __shared__ __align__(16) unsigned short Ks[2][64 * 64];
    __shared__ __align__(16) unsigned short Vs[2][64 * 64];
    __shared__ __align__(16) unsigned short Pl[4][32 * 64];

    const int bid = blockIdx.x;
    int bh, qt, kt0, ktend, ck;
    bool direct;
    if (bid < 256) {
        bh = bid & 31; qt = 8 + (bid >> 5);
        kt0 = 0; ktend = 16; ck = 0; direct = false;
    } else if (bid < 512) {
        int j = bid - 256;
        bh = j & 31; qt = 7 - (j >> 5);
        kt0 = 0; ktend = 2 * qt + 2; ck = 0; direct = true;
    } else {
        int j = bid - 512;
        bh = j & 31; qt = 15 - (j >> 5);
        kt0 = 16; ktend = 2 * qt + 2; ck = 1; direct = false;
    }
    const int nkt = ktend - kt0;
    const int h = bh & 15, b = bh >> 4, kv = h >> 2;
    const int tid = threadIdx.x;
    const int w = tid >> 6, l = tid & 63;
    const int lk = l & 15, lg = l >> 4;

    const unsigned short* Kb = K + ((size_t)(b * 4 + kv)) * T_ * 64;
    const unsigned short* Vb = Vt + ((size_t)(b * 4 + kv)) * 64 * T_;

    // Q fragments: 2 m-tiles of 16 rows each (wave covers 32 q-rows)
    short8 af[2][2];
    #pragma unroll
    for (int m = 0; m < 2; ++m) {
        const unsigned short* qp =
            Q + (((size_t)(b * 16 + h)) * T_ + qt * 128 + w * 32 + m * 16 + lk) * 64 + lg * 8;
        af[m][0] = *(const short8*)(qp);
        af[m][1] = *(const short8*)(qp + 32);
    }

    f32x4 acc[2][4];
    f32x4 lacc[2];
    float mrow[2][4];
    #pragma unroll
    for (int m = 0; m < 2; ++m) {
        lacc[m] = (f32x4){0, 0, 0, 0};
        #pragma unroll
        for (int db = 0; db < 4; ++db) acc[m][db] = (f32x4){0, 0, 0, 0};
        #pragma unroll
        for (int r = 0; r < 4; ++r) mrow[m][r] = -1e38f;
    }

    short8 ones;
    #pragma unroll
    for (int i = 0; i < 8; ++i) ones[i] = (short)0x3F80;   // bf16 1.0

    // async staging: chunk ch = 64 lanes x 16B = rows ch*8..+7 (8 rows), linear
    // LDS dest; global source chunk pre-swizzled: g_src = sg ^ (row&7)
    const int sr = l >> 3;        // row within chunk
    const int sg = l & 7;         // 16B-chunk col
    auto stage = [&](int buf, int kt) {
        #pragma unroll
        for (int p = 0; p < 2; ++p) {
            const int ch = w * 2 + p;
            const int row = ch * 8 + sr;
            const int gs = (sg ^ sr) * 8;     // row&7 == sr
            gl_lds16(Kb + ((size_t)(kt * 64 + row)) * 64 + gs, &Ks[buf][ch * 512]);
            gl_lds16(Vb + (size_t)row * T_ + kt * 64 + gs,     &Vs[buf][ch * 512]);
        }
    };

    stage(0, kt0);
    for (int i = 0; i < nkt; ++i) {
        const int kt = kt0 + i;
        const int cur = i & 1;
        __syncthreads();                       // drains DMA: buf[cur] ready
        if (i + 1 < nkt) stage(cur ^ 1, kt0 + i + 1);

        // ---- S = Q K^T  (K fragments shared across both m-tiles)
        float s4[2][4][4];
        __builtin_amdgcn_s_setprio(1);
        #pragma unroll
        for (int nt = 0; nt < 4; ++nt) {
            const int row = nt * 16 + lk;
            short8 b0 = *(const short8*)&Ks[cur][row * 64 + SWC(row, lg * 8)];
            short8 b1 = *(const short8*)&Ks[cur][row * 64 + SWC(row, 32 + lg * 8)];
            f32x4 c0 = {0, 0, 0, 0}, c1 = {0, 0, 0, 0};
            c0 = __builtin_amdgcn_mfma_f32_16x16x32_bf16(af[0][0], b0, c0, 0, 0, 0);
            c1 = __builtin_amdgcn_mfma_f32_16x16x32_bf16(af[1][0], b0, c1, 0, 0, 0);
            c0 = __builtin_amdgcn_mfma_f32_16x16x32_bf16(af[0][1], b1, c0, 0, 0, 0);
            c1 = __builtin_amdgcn_mfma_f32_16x16x32_bf16(af[1][1], b1, c1, 0, 0, 0);
            #pragma unroll
            for (int r = 0; r < 4; ++r) { s4[0][nt][r] = c0[r]; s4[1][nt][r] = c1[r]; }
        }
        __builtin_amdgcn_s_setprio(0);

        if (kt >= 2 * qt) {                    // diagonal region mask
            #pragma unroll
            for (int m = 0; m < 2; ++m) {
                const int qg = qt * 128 + w * 32 + m * 16 + lg * 4;
                #pragma unroll
                for (int nt = 0; nt < 4; ++nt) {
                    const int kg = kt * 64 + nt * 16 + lk;
                    #pragma unroll
                    for (int r = 0; r < 4; ++r)
                        if (kg > qg + r) s4[m][nt][r] = -1e30f;
                }
            }
        }

        // ---- defer-max: lane-local check, shuffle reduce only when tripped
        float lm[2][4];
        bool need = false;
        #pragma unroll
        for (int m = 0; m < 2; ++m)
            #pragma unroll
            for (int r = 0; r < 4; ++r) {
                lm[m][r] = fmaxf(fmaxf(s4[m][0][r], s4[m][1][r]),
                                 fmaxf(s4[m][2][r], s4[m][3][r]));
                need = need || (lm[m][r] > mrow[m][r] + DEFER);
            }
        if (__any(need)) {
            #pragma unroll
            for (int m = 0; m < 2; ++m)
                #pragma unroll
                for (int r = 0; r < 4; ++r) {
                    float v = lm[m][r];
                    v = fmaxf(v, __shfl_xor(v, 1));
                    v = fmaxf(v, __shfl_xor(v, 2));
                    v = fmaxf(v, __shfl_xor(v, 4));
                    v = fmaxf(v, __shfl_xor(v, 8));
                    float nm = fmaxf(mrow[m][r], v);
                    float corr = exp2f(mrow[m][r] - nm);
                    mrow[m][r] = nm;
                    #pragma unroll
                    for (int db = 0; db < 4; ++db) acc[m][db][r] *= corr;
                    lacc[m][r] *= corr;
                }
        }
        #pragma unroll
        for (int m = 0; m < 2; ++m)
            #pragma unroll
            for (int r = 0; r < 4; ++r)
                #pragma unroll
                for (int nt = 0; nt < 4; ++nt)
                    s4[m][nt][r] = exp2f(s4[m][nt][r] - mrow[m][r]);

        // ---- P -> LDS (swizzled)
        #pragma unroll
        for (int m = 0; m < 2; ++m)
            #pragma unroll
            for (int nt = 0; nt < 4; ++nt)
                #pragma unroll
                for (int r = 0; r < 4; ++r) {
                    const int row = m * 16 + lg * 4 + r;
                    Pl[w][row * 64 + SWC(row, nt * 16 + lk)] = f2bf(s4[m][nt][r]);
                }

        // ---- O += P V ; lsum += P 1   (V fragments shared across m-tiles)
        __builtin_amdgcn_s_setprio(1);
        #pragma unroll
        for (int kk = 0; kk < 2; ++kk) {
            const int pr0 = lk, pr1 = 16 + lk;
            short8 pa0 = *(const short8*)&Pl[w][pr0 * 64 + SWC(pr0, kk * 32 + lg * 8)];
            short8 pa1 = *(const short8*)&Pl[w][pr1 * 64 + SWC(pr1, kk * 32 + lg * 8)];
            lacc[0] = __builtin_amdgcn_mfma_f32_16x16x32_bf16(pa0, ones, lacc[0], 0, 0, 0);
            lacc[1] = __builtin_amdgcn_mfma_f32_16x16x32_bf16(pa1, ones, lacc[1], 0, 0, 0);
            #pragma unroll
            for (int db = 0; db < 4; ++db) {
                const int vrow = db * 16 + lk;
                short8 vb = *(const short8*)&Vs[cur][vrow * 64 + SWC(vrow, kk * 32 + lg * 8)];
                acc[0][db] = __builtin_amdgcn_mfma_f32_16x16x32_bf16(pa0, vb, acc[0][db], 0, 0, 0);
                acc[1][db] = __builtin_amdgcn_mfma_f32_16x16x32_bf16(pa1, vb, acc[1][db], 0, 0, 0);
            }
        }
        __builtin_amdgcn_s_setprio(0);
    }

    if (direct) {
        #pragma unroll
        for (int m = 0; m < 2; ++m)
            #pragma unroll
            for (int r = 0; r < 4; ++r) {
                float inv = 1.f / lacc[m][r];
                int t = qt * 128 + w * 32 + m * 16 + lg * 4 + r;
                #pragma unroll
                for (int db = 0; db < 4; ++db)
                    O[(((size_t)(b * T_ + t)) * 16 + h) * 64 + db * 16 + lk] =
                        f2bf(acc[m][db][r] * inv);
            }
    } else {
        const int p = ((bh << 3) + (qt - 8)) * 2 + ck;
        #pragma unroll
        for (int m = 0; m < 2; ++m)
            #pragma unroll
            for (int r = 0; r < 4; ++r) {
                const int row = w * 32 + m * 16 + lg * 4 + r;
                if (lk == 0) {
                    PM[p * 128 + row]  = mrow[m][r];
                    PLp[p * 128 + row] = lacc[m][r];
                }
                #pragma unroll
                for (int db = 0; db < 4; ++db)
                    PACC[((size_t)p * 128 + row) * 64 + db * 16 + lk] = f2bf(acc[m][db][r]);
            }
    }
}

// ---------------------------------------------------------------------------
// Combine two split-K partials per (b,h,long-qt).  256 blocks x 256 threads.
// ---------------------------------------------------------------------------
__global__ __launch_bounds__(256) void combine_attn(
        const float* __restrict__ PM, const float* __restrict__ PLp,
        const unsigned short* __restrict__ PACC,
        unsigned short* __restrict__ O) {
    const int cid = blockIdx.x;
    const int bh = cid & 31, qt = 8 + (cid >> 5);
    const int h = bh & 15, b = bh >> 4;
    const int tid = threadIdx.x;
    const int row = tid >> 1, cg = (tid & 1) * 32;
    const int p0 = ((bh << 3) + (qt - 8)) * 2, p1 = p0 + 1;

    float mA = PM[p0 * 128 + row], mB = PM[p1 * 128 + row];
    float lA = PLp[p0 * 128 + row], lB = PLp[p1 * 128 + row];
    float M = fmaxf(mA, mB);
    float wA = exp2f(mA - M), wB = exp2f(mB - M);
    float inv = 1.f / (lA * wA + lB * wB);
    wA *= inv; wB *= inv;

    const unsigned short* a = &PACC[((size_t)p0 * 128 + row) * 64 + cg];
    const unsigned short* c = &PACC[((size_t)p1 * 128 + row) * 64 + cg];
    int t = qt * 128 + row;
    unsigned short* op = &O[(((size_t)(b * T_ + t)) * 16 + h) * 64 + cg];
    #pragma unroll
    for (int j = 0; j < 4; ++j) {
        short8 va = *(const short8*)(a + j * 8);
        short8 vb = *(const short8*)(c + j * 8);
        short8 o;
        #pragma unroll
        for (int i = 0; i < 8; ++i)
            o[i] = f2bf(bf2f((unsigned short)va[i]) * wA +
                        bf2f((unsigned short)vb[i]) * wB);
        *(short8*)(op + j * 8) = o;
    }
}

// ---------------------------------------------------------------------------
extern "C" void kernel_launch(void* const* d_in, const int* in_sizes, int n_in,
                              void* d_out, int out_size, void* d_ws, size_t ws_size,
                              hipStream_t stream) {
    const float* x  = (const float*)d_in[0];
    const float* rc = (const float*)d_in[1];
    const float* rs = (const float*)d_in[2];
    const float* Wq = (const float*)d_in[4];
    const float* Wk = (const float*)d_in[5];
    const float* Wv = (const float*)d_in[6];
    const float* Wo = (const float*)d_in[7];
    float* out = (float*)d_out;

    unsigned short* ws = (unsigned short*)d_ws;
    unsigned short* xb  = ws;                        // 4M shorts (dead after QKV)
    unsigned short* Wt  = ws + 4194304;              // 1.5M (dead after QKV)
    unsigned short* Wot = ws + 5767168;              // 1M
    unsigned short* Qbf = ws + 6815744;              // 4M
    unsigned short* Kbf = ws + 11010048;             // 1M
    unsigned short* Vtb = ws + 12058624;             // 1M
    unsigned short* Ob  = ws + 13107200;             // 4M

    // split-K partials reuse the dead xb/Wt region: 256K+256K+8M < 11M
    float* PM            = (float*)d_ws;                         // [512][128] f32
    float* PLp           = PM + 512 * 128;                       // [512][128] f32
    unsigned short* PACC = (unsigned short*)(PLp + 512 * 128);   // [512][128][64] bf16

    dim3 blk(256);
    cast_bf16<<<2048, blk, 0, stream>>>(x, xb, 524288);
    transpose_cast<<<dim3(16, 16), blk, 0, stream>>>(Wq, Wt, 1024, 1024, 0);
    transpose_cast<<<dim3(4, 16),  blk, 0, stream>>>(Wk, Wt, 1024, 256, 1024);
    transpose_cast<<<dim3(4, 16),  blk, 0, stream>>>(Wv, Wt, 1024, 256, 1280);
    transpose_cast<<<dim3(16, 16), blk, 0, stream>>>(Wo, Wot, 1024, 1024, 0);

    gemm_mfma<1><<<dim3(24, 32), blk, 0, stream>>>(
        xb, Wt, (void*)Qbf, Kbf, Vtb, rc, rs, 4096, 1536, 1024);

    attn_mfma<<<dim3(768), blk, 0, stream>>>(Qbf, Kbf, Vtb, Ob, PM, PLp, PACC);
    combine_attn<<<dim3(256), blk, 0, stream>>>(PM, PLp, PACC, Ob);

    gemm_mfma<0><<<dim3(16, 32), blk, 0, stream>>>(
        Ob, Wot, (void*)out, nullptr, nullptr, nullptr, nullptr, 4096, 1024, 1024);
}

// Round 10
// 120.024 us; speedup vs baseline: 1.1128x; 1.0497x over previous
//
#include <hip/hip_runtime.h>

typedef __attribute__((ext_vector_type(8))) short short8;
typedef __attribute__((ext_vector_type(4))) short short4v;
typedef __attribute__((ext_vector_type(4))) float f32x4;
typedef __attribute__((ext_vector_type(16))) float f32x16;
typedef __attribute__((ext_vector_type(2))) unsigned uint2v;
typedef __attribute__((ext_vector_type(4))) unsigned uint4v;

#define T_ 2048
#define H_ 16
#define KVH_ 4
#define QSCALE 0.18033688011112042f   // 0.125 * log2(e): softmax in base-2 domain
#define DEFER 8.0f                    // T13 defer-max threshold (log2 domain)

__device__ inline unsigned short f2bf(float f) {
    unsigned u = __builtin_bit_cast(unsigned, f);
    u += 0x7fff + ((u >> 16) & 1);
    return (unsigned short)(u >> 16);
}
__device__ inline float bf2f(unsigned short v) {
    unsigned u = ((unsigned)v) << 16;
    return __builtin_bit_cast(float, u);
}
__device__ inline unsigned pk2(float lo, float hi) {
    unsigned r;
    asm("v_cvt_pk_bf16_f32 %0, %1, %2" : "=v"(r) : "v"(lo), "v"(hi));
    return r;
}

__device__ inline void gl_lds16(const unsigned short* g, unsigned short* lds) {
    __builtin_amdgcn_global_load_lds(
        (const __attribute__((address_space(1))) unsigned int*)g,
        (__attribute__((address_space(3))) unsigned int*)lds, 16, 0, 0);
}

// ---------------------------------------------------------------------------
// f32 -> bf16 straight cast (8 elems/thread)
// ---------------------------------------------------------------------------
__global__ void cast_bf16(const float* __restrict__ in,
                          unsigned short* __restrict__ out, int n8) {
    int i = blockIdx.x * blockDim.x + threadIdx.x;
    if (i >= n8) return;
    float4 v0 = ((const float4*)in)[i * 2];
    float4 v1 = ((const float4*)in)[i * 2 + 1];
    short8 o;
    o[0] = f2bf(v0.x); o[1] = f2bf(v0.y); o[2] = f2bf(v0.z); o[3] = f2bf(v0.w);
    o[4] = f2bf(v1.x); o[5] = f2bf(v1.y); o[6] = f2bf(v1.z); o[7] = f2bf(v1.w);
    ((short8*)out)[i] = o;
}

// ---------------------------------------------------------------------------
// W [K][N] f32  ->  out [rowoff + N][K] bf16   (transpose + cast), 64x64 tiles
// ---------------------------------------------------------------------------
__global__ __launch_bounds__(256) void transpose_cast(
        const float* __restrict__ W, unsigned short* __restrict__ out,
        int K, int N, int rowoff) {
    __shared__ unsigned short ts[64][66];
    const int bx = blockIdx.x, by = blockIdx.y, tid = threadIdx.x;
    #pragma unroll
    for (int s = 0; s < 16; ++s) {
        int idx = tid + s * 256;
        int kl = idx >> 6, nl = idx & 63;
        ts[kl][nl] = f2bf(W[(size_t)(by * 64 + kl) * N + bx * 64 + nl]);
    }
    __syncthreads();
    #pragma unroll
    for (int s = 0; s < 16; ++s) {
        int idx = tid + s * 256;
        int nl = idx >> 6, kl = idx & 63;
        out[(size_t)(rowoff + bx * 64 + nl) * K + by * 64 + kl] = ts[kl][nl];
    }
}

// ---------------------------------------------------------------------------
// bf16 MFMA GEMM, 128x64 tile, BK=32, global_load_lds staging, 4 waves x 32row.
// MODE 0: C = f32 [M][1024]  (O projection)
// MODE 1: merged QKV (N=1536): col-group <16: Q RoPE*QSCALE -> Cq [B][16][T][64]
//         16..19: K RoPE -> Ck [B][4][T][64];  20..23: V -> Cvt [B][4][64][T]
// ---------------------------------------------------------------------------
template <int MODE>
__global__ __launch_bounds__(256) void gemm_mfma(
        const unsigned short* __restrict__ A,
        const unsigned short* __restrict__ Bt,
        void* __restrict__ Cq, unsigned short* __restrict__ Ck,
        unsigned short* __restrict__ Cvt,
        const float* __restrict__ rc, const float* __restrict__ rs,
        int M, int N, int K) {
    __shared__ __align__(16) unsigned short As[128 * 32];
    __shared__ __align__(16) unsigned short Bs[64 * 32];
    const int tid = threadIdx.x;
    const int w = tid >> 6, l = tid & 63, lk = l & 15, lg = l >> 4;
    const int bx = blockIdx.x, by = blockIdx.y;

    const unsigned short* Arow = A + (size_t)by * 128 * K;
    const unsigned short* Brow = Bt + (size_t)bx * 64 * K;

    f32x4 acc[2][4];
    #pragma unroll
    for (int m = 0; m < 2; ++m)
        #pragma unroll
        for (int n = 0; n < 4; ++n) acc[m][n] = (f32x4){0, 0, 0, 0};

    for (int k0 = 0; k0 < K; k0 += 32) {
        #pragma unroll
        for (int p = 0; p < 2; ++p) {
            int cb = p * 256 + w * 64;
            int c = cb + l;
            int row = c >> 2, ko = (c & 3) * 8;
            gl_lds16(Arow + (size_t)row * K + k0 + ko, As + cb * 8);
        }
        {
            int c = w * 64 + l;
            int row = c >> 2, ko = (c & 3) * 8;
            gl_lds16(Brow + (size_t)row * K + k0 + ko, Bs + c * 8);
        }
        __syncthreads();
        short8 aF[2], bF[4];
        #pragma unroll
        for (int m = 0; m < 2; ++m)
            aF[m] = *(const short8*)&As[(w * 32 + m * 16 + lk) * 32 + lg * 8];
        #pragma unroll
        for (int n = 0; n < 4; ++n)
            bF[n] = *(const short8*)&Bs[(n * 16 + lk) * 32 + lg * 8];
        #pragma unroll
        for (int m = 0; m < 2; ++m)
            #pragma unroll
            for (int n = 0; n < 4; ++n)
                acc[m][n] = __builtin_amdgcn_mfma_f32_16x16x32_bf16(
                    aF[m], bF[n], acc[m][n], 0, 0, 0);
        __syncthreads();
    }

    const int rowbase = by * 128 + w * 32;
    if constexpr (MODE == 0) {
        float* C = (float*)Cq;
        #pragma unroll
        for (int m = 0; m < 2; ++m)
            #pragma unroll
            for (int r = 0; r < 4; ++r) {
                size_t ro = (size_t)(rowbase + m * 16 + lg * 4 + r) * N + bx * 64 + lk;
                #pragma unroll
                for (int n = 0; n < 4; ++n) C[ro + n * 16] = acc[m][n][r];
            }
    }
    if constexpr (MODE == 1) {
        const int colgrp = bx;              // 64-col group over N=1536
        if (colgrp < 16) {                  // ---- Q: RoPE * QSCALE
            unsigned short* C = (unsigned short*)Cq;
            const int h = colgrp;
            #pragma unroll
            for (int m = 0; m < 2; ++m)
                #pragma unroll
                for (int r = 0; r < 4; ++r) {
                    int trow = rowbase + m * 16 + lg * 4 + r;
                    int b = trow >> 11, t = trow & (T_ - 1);
                    size_t ob = (((size_t)(b * 16 + h)) * T_ + t) * 64;
                    #pragma unroll
                    for (int n = 0; n < 2; ++n) {
                        int d = n * 16 + lk;
                        float cc = rc[t * 32 + d], ss = rs[t * 32 + d];
                        float x1 = acc[m][n][r], x2 = acc[m][n + 2][r];
                        C[ob + d]      = f2bf((x1 * cc - x2 * ss) * QSCALE);
                        C[ob + d + 32] = f2bf((x2 * cc + x1 * ss) * QSCALE);
                    }
                }
        } else if (colgrp < 20) {           // ---- K: RoPE
            const int kvh = colgrp - 16;
            #pragma unroll
            for (int m = 0; m < 2; ++m)
                #pragma unroll
                for (int r = 0; r < 4; ++r) {
                    int trow = rowbase + m * 16 + lg * 4 + r;
                    int b = trow >> 11, t = trow & (T_ - 1);
                    size_t ob = (((size_t)(b * 4 + kvh)) * T_ + t) * 64;
                    #pragma unroll
                    for (int n = 0; n < 2; ++n) {
                        int d = n * 16 + lk;
                        float cc = rc[t * 32 + d], ss = rs[t * 32 + d];
                        float x1 = acc[m][n][r], x2 = acc[m][n + 2][r];
                        Ck[ob + d]      = f2bf(x1 * cc - x2 * ss);
                        Ck[ob + d + 32] = f2bf(x2 * cc + x1 * ss);
                    }
                }
        } else {                            // ---- V -> [B][4][64][T]
            const int kvh = colgrp - 20;
            #pragma unroll
            for (int m = 0; m < 2; ++m) {
                int trow0 = rowbase + m * 16 + lg * 4;
                int b = trow0 >> 11, t0 = trow0 & (T_ - 1);
                #pragma unroll
                for (int n = 0; n < 4; ++n) {
                    int d = n * 16 + lk;
                    short4v pk;
                    #pragma unroll
                    for (int r = 0; r < 4; ++r) pk[r] = f2bf(acc[m][n][r]);
                    *(short4v*)(Cvt + (((size_t)(b * 4 + kvh)) * 64 + d) * T_ + t0) = pk;
                }
            }
        }
    }
}

// ---------------------------------------------------------------------------
// Flash attention v7: swapped QK^T (S^T = K*Q via mfma_32x32x16) -> softmax
// fully in-register (lane owns one q-row); P->PV A-frags via cvt_pk +
// permlane32_swap (no P LDS round-trip, no lsum MFMA). 4 waves x 32 q-rows.
// Split-K mapping, staging, combine: unchanged from v6.
//   C/D layout 32x32: col=lane&31, row=crow(r,hi)=(r&3)+8*(r>>2)+4*hi
//   A/B frag: row/col=lane&31, k=(lane>>5)*8+j
// ---------------------------------------------------------------------------
#define SWC(row, col) ((col) ^ (((row) & 7) << 3))
#define CROW(r, hi) (((r) & 3) + 8 * ((r) >> 2) + 4 * (hi))

__global__ __launch_bounds__(256) void attn_mfma(
        const unsigned short* __restrict__ Q,   // [B][16][T][64] (pre-scaled, log2 domain)
        const unsigned short* __restrict__ K,   // [B][4][T][64]
        const unsigned short* __restrict__ Vt,  // [B][4][64][T]
        unsigned short* __restrict__ O,         // [B*T][16][64] bf16
        float* __restrict__ PM, float* __restrict__ PLp,
        unsigned short* __restrict__ PACC) {
    __shared__ __align__(16) unsigned short Ks[2][64 * 64];
    __shared__ __align__(16) unsigned short Vs[2][64 * 64];

    const int bid = blockIdx.x;
    int bh, qt, kt0, ktend, ck;
    bool direct;
    if (bid < 256) {
        bh = bid & 31; qt = 8 + (bid >> 5);
        kt0 = 0; ktend = 16; ck = 0; direct = false;
    } else if (bid < 512) {
        int j = bid - 256;
        bh = j & 31; qt = 7 - (j >> 5);
        kt0 = 0; ktend = 2 * qt + 2; ck = 0; direct = true;
    } else {
        int j = bid - 512;
        bh = j & 31; qt = 15 - (j >> 5);
        kt0 = 16; ktend = 2 * qt + 2; ck = 1; direct = false;
    }
    const int nkt = ktend - kt0;
    const int h = bh & 15, b = bh >> 4, kv = h >> 2;
    const int tid = threadIdx.x;
    const int w = tid >> 6, l = tid & 63;
    const int q32 = l & 31, hi = l >> 5;

    const unsigned short* Kb = K + ((size_t)(b * 4 + kv)) * T_ * 64;
    const unsigned short* Vb = Vt + ((size_t)(b * 4 + kv)) * 64 * T_;

    // Q B-frags: B[k=d][n=q]: lane holds q=l&31, d=16s+hi*8+j
    short8 qf[4];
    {
        const unsigned short* qp =
            Q + (((size_t)(b * 16 + h)) * T_ + qt * 128 + w * 32 + q32) * 64 + hi * 8;
        #pragma unroll
        for (int s = 0; s < 4; ++s) qf[s] = *(const short8*)(qp + 16 * s);
    }

    f32x16 o0, o1;                // O^T: col d = dt*32+q32, rows q = crow(r,hi)
    #pragma unroll
    for (int i = 0; i < 16; ++i) { o0[i] = 0.f; o1[i] = 0.f; }
    float mloc = -1e38f, lsum = 0.f;

    // staging: linear LDS dest, pre-swizzled global source (m173 pattern)
    const int sr = l >> 3, sg = l & 7;
    auto stage = [&](int buf, int kt) {
        #pragma unroll
        for (int p = 0; p < 2; ++p) {
            const int ch = w * 2 + p;
            const int row = ch * 8 + sr;
            const int gs = (sg ^ sr) * 8;
            gl_lds16(Kb + ((size_t)(kt * 64 + row)) * 64 + gs, &Ks[buf][ch * 512]);
            gl_lds16(Vb + (size_t)row * T_ + kt * 64 + gs,     &Vs[buf][ch * 512]);
        }
    };

    // build PV A-frag word group from 8 P values (post-exp2, q=lane-local)
    auto mk = [&](float e0, float e1, float e2, float e3,
                  float e4, float e5, float e6, float e7) -> short8 {
        unsigned a0 = pk2(e0, e1);
        unsigned b0 = pk2(e4, e5);
        uint2v r02 = __builtin_amdgcn_permlane32_swap(a0, b0, false, false);
        unsigned a1 = pk2(e2, e3);
        unsigned b1 = pk2(e6, e7);
        uint2v r13 = __builtin_amdgcn_permlane32_swap(a1, b1, false, false);
        uint4v u;
        u[0] = r02[0]; u[1] = r13[0]; u[2] = r02[1]; u[3] = r13[1];
        return __builtin_bit_cast(short8, u);
    };

    stage(0, kt0);
    for (int i = 0; i < nkt; ++i) {
        const int kt = kt0 + i;
        const int cur = i & 1;
        __syncthreads();                       // DMA drained: buf[cur] ready
        if (i + 1 < nkt) stage(cur ^ 1, kt0 + i + 1);

        // ---- S^T = K Q  (A=K rows k, B=Q cols q); two 32-k subtiles
        f32x16 st0, st1;
        #pragma unroll
        for (int r = 0; r < 16; ++r) { st0[r] = 0.f; st1[r] = 0.f; }
        __builtin_amdgcn_s_setprio(1);
        #pragma unroll
        for (int s = 0; s < 4; ++s) {
            const int c = 16 * s + hi * 8;
            const int kr0 = q32, kr1 = 32 + q32;
            short8 k0 = *(const short8*)&Ks[cur][kr0 * 64 + SWC(kr0, c)];
            short8 k1 = *(const short8*)&Ks[cur][kr1 * 64 + SWC(kr1, c)];
            st0 = __builtin_amdgcn_mfma_f32_32x32x16_bf16(k0, qf[s], st0, 0, 0, 0);
            st1 = __builtin_amdgcn_mfma_f32_32x32x16_bf16(k1, qf[s], st1, 0, 0, 0);
        }
        __builtin_amdgcn_s_setprio(0);

        if (kt >= 2 * qt) {                    // diagonal region mask
            const int qg = qt * 128 + w * 32 + q32;
            #pragma unroll
            for (int r = 0; r < 16; ++r) {
                const int kg = kt * 64 + CROW(r, hi);
                if (kg > qg)      st0[r] = -1e30f;
                if (kg + 32 > qg) st1[r] = -1e30f;
            }
        }

        // ---- row max: lane-local 31 fmax + one cross-half exchange
        float pm = st0[0];
        #pragma unroll
        for (int r = 1; r < 16; ++r) pm = fmaxf(pm, st0[r]);
        #pragma unroll
        for (int r = 0; r < 16; ++r) pm = fmaxf(pm, st1[r]);
        pm = fmaxf(pm, __shfl_xor(pm, 32));

        // ---- defer-max rescale (rare)
        if (__any(pm > mloc + DEFER)) {
            const float nm = fmaxf(mloc, pm);
            const float corr = exp2f(mloc - nm);
            mloc = nm;
            lsum *= corr;
            #pragma unroll
            for (int r = 0; r < 16; ++r) {
                const float cr = __shfl(corr, CROW(r, hi));
                o0[r] *= cr;
                o1[r] *= cr;
            }
        }

        // ---- exp2 + lane-local sum
        float ls = 0.f;
        #pragma unroll
        for (int r = 0; r < 16; ++r) {
            st0[r] = exp2f(st0[r] - mloc); ls += st0[r];
            st1[r] = exp2f(st1[r] - mloc); ls += st1[r];
        }
        ls += __shfl_xor(ls, 32);
        lsum += ls;

        // ---- P -> PV A-frags (16 cvt_pk + 8 permlane32_swap, no LDS)
        short8 pa0 = mk(st0[0], st0[1], st0[2],  st0[3],  st0[4],  st0[5],  st0[6],  st0[7]);
        short8 pa1 = mk(st0[8], st0[9], st0[10], st0[11], st0[12], st0[13], st0[14], st0[15]);
        short8 pa2 = mk(st1[0], st1[1], st1[2],  st1[3],  st1[4],  st1[5],  st1[6],  st1[7]);
        short8 pa3 = mk(st1[8], st1[9], st1[10], st1[11], st1[12], st1[13], st1[14], st1[15]);

        // ---- O^T += P V  (B = V[k][d] read from Vs = V^T[d][k])
        __builtin_amdgcn_s_setprio(1);
        const int vd0 = q32, vd1 = 32 + q32;
        #pragma unroll
        for (int ks = 0; ks < 4; ++ks) {
            short8 paf = (ks == 0) ? pa0 : (ks == 1) ? pa1 : (ks == 2) ? pa2 : pa3;
            const int c = 16 * ks + hi * 8;
            short8 vb0 = *(const short8*)&Vs[cur][vd0 * 64 + SWC(vd0, c)];
            short8 vb1 = *(const short8*)&Vs[cur][vd1 * 64 + SWC(vd1, c)];
            o0 = __builtin_amdgcn_mfma_f32_32x32x16_bf16(paf, vb0, o0, 0, 0, 0);
            o1 = __builtin_amdgcn_mfma_f32_32x32x16_bf16(paf, vb1, o1, 0, 0, 0);
        }
        __builtin_amdgcn_s_setprio(0);
    }

    if (direct) {
        #pragma unroll
        for (int r = 0; r < 16; ++r) {
            const float inv = 1.f / __shfl(lsum, CROW(r, hi));
            const int t = qt * 128 + w * 32 + CROW(r, hi);
            unsigned short* op = &O[(((size_t)(b * T_ + t)) * 16 + h) * 64 + q32];
            op[0]  = f2bf(o0[r] * inv);
            op[32] = f2bf(o1[r] * inv);
        }
    } else {
        const int p = ((bh << 3) + (qt - 8)) * 2 + ck;
        if (l < 32) {
            PM[p * 128 + w * 32 + l]  = mloc;
            PLp[p * 128 + w * 32 + l] = lsum;
        }
        #pragma unroll
        for (int r = 0; r < 16; ++r) {
            const int row = w * 32 + CROW(r, hi);
            unsigned short* pp = &PACC[((size_t)p * 128 + row) * 64 + q32];
            pp[0]  = f2bf(o0[r]);
            pp[32] = f2bf(o1[r]);
        }
    }
}

// ---------------------------------------------------------------------------
// Combine two split-K partials per (b,h,long-qt).  256 blocks x 256 threads.
// ---------------------------------------------------------------------------
__global__ __launch_bounds__(256) void combine_attn(
        const float* __restrict__ PM, const float* __restrict__ PLp,
        const unsigned short* __restrict__ PACC,
        unsigned short* __restrict__ O) {
    const int cid = blockIdx.x;
    const int bh = cid & 31, qt = 8 + (cid >> 5);
    const int h = bh & 15, b = bh >> 4;
    const int tid = threadIdx.x;
    const int row = tid >> 1, cg = (tid & 1) * 32;
    const int p0 = ((bh << 3) + (qt - 8)) * 2, p1 = p0 + 1;

    float mA = PM[p0 * 128 + row], mB = PM[p1 * 128 + row];
    float lA = PLp[p0 * 128 + row], lB = PLp[p1 * 128 + row];
    float M = fmaxf(mA, mB);
    float wA = exp2f(mA - M), wB = exp2f(mB - M);
    float inv = 1.f / (lA * wA + lB * wB);
    wA *= inv; wB *= inv;

    const unsigned short* a = &PACC[((size_t)p0 * 128 + row) * 64 + cg];
    const unsigned short* c = &PACC[((size_t)p1 * 128 + row) * 64 + cg];
    int t = qt * 128 + row;
    unsigned short* op = &O[(((size_t)(b * T_ + t)) * 16 + h) * 64 + cg];
    #pragma unroll
    for (int j = 0; j < 4; ++j) {
        short8 va = *(const short8*)(a + j * 8);
        short8 vb = *(const short8*)(c + j * 8);
        short8 o;
        #pragma unroll
        for (int i = 0; i < 8; ++i)
            o[i] = f2bf(bf2f((unsigned short)va[i]) * wA +
                        bf2f((unsigned short)vb[i]) * wB);
        *(short8*)(op + j * 8) = o;
    }
}

// ---------------------------------------------------------------------------
extern "C" void kernel_launch(void* const* d_in, const int* in_sizes, int n_in,
                              void* d_out, int out_size, void* d_ws, size_t ws_size,
                              hipStream_t stream) {
    const float* x  = (const float*)d_in[0];
    const float* rc = (const float*)d_in[1];
    const float* rs = (const float*)d_in[2];
    const float* Wq = (const float*)d_in[4];
    const float* Wk = (const float*)d_in[5];
    const float* Wv = (const float*)d_in[6];
    const float* Wo = (const float*)d_in[7];
    float* out = (float*)d_out;

    unsigned short* ws = (unsigned short*)d_ws;
    unsigned short* xb  = ws;                        // 4M shorts (dead after QKV)
    unsigned short* Wt  = ws + 4194304;              // 1.5M (dead after QKV)
    unsigned short* Wot = ws + 5767168;              // 1M
    unsigned short* Qbf = ws + 6815744;              // 4M
    unsigned short* Kbf = ws + 11010048;             // 1M
    unsigned short* Vtb = ws + 12058624;             // 1M
    unsigned short* Ob  = ws + 13107200;             // 4M

    // split-K partials reuse the dead xb/Wt region
    float* PM            = (float*)d_ws;                         // [512][128] f32
    float* PLp           = PM + 512 * 128;                       // [512][128] f32
    unsigned short* PACC = (unsigned short*)(PLp + 512 * 128);   // [512][128][64] bf16

    dim3 blk(256);
    cast_bf16<<<2048, blk, 0, stream>>>(x, xb, 524288);
    transpose_cast<<<dim3(16, 16), blk, 0, stream>>>(Wq, Wt, 1024, 1024, 0);
    transpose_cast<<<dim3(4, 16),  blk, 0, stream>>>(Wk, Wt, 1024, 256, 1024);
    transpose_cast<<<dim3(4, 16),  blk, 0, stream>>>(Wv, Wt, 1024, 256, 1280);
    transpose_cast<<<dim3(16, 16), blk, 0, stream>>>(Wo, Wot, 1024, 1024, 0);

    gemm_mfma<1><<<dim3(24, 32), blk, 0, stream>>>(
        xb, Wt, (void*)Qbf, Kbf, Vtb, rc, rs, 4096, 1536, 1024);

    attn_mfma<<<dim3(768), blk, 0, stream>>>(Qbf, Kbf, Vtb, Ob, PM, PLp, PACC);
    combine_attn<<<dim3(256), blk, 0, stream>>>(PM, PLp, PACC, Ob);

    gemm_mfma<0><<<dim3(16, 32), blk, 0, stream>>>(
        Ob, Wot, (void*)out, nullptr, nullptr, nullptr, nullptr, 4096, 1024, 1024);
}